// Round 2
// baseline (2767.037 us; speedup 1.0000x reference)
//
#include <hip/hip_runtime.h>
#include <hip/hip_bf16.h>

// ---------------------------------------------------------------------------
// Encoder: B=4, S=2048, V=32000, D=512, F=2048, L=6, H=8, Dh=64
// Inputs/outputs are fp32 on the wire. Internally: bf16 MFMA GEMMs with fp32
// accumulators; residual stream kept in fp32 master + bf16 shadow.
// ---------------------------------------------------------------------------

typedef unsigned short u16;
typedef __bf16 bf16x8 __attribute__((ext_vector_type(8)));
typedef float f32x4 __attribute__((ext_vector_type(4)));
typedef unsigned short u16x8 __attribute__((ext_vector_type(8)));

#define S_LEN 2048
#define DM 512
#define FF 2048
#define NHEAD 8

__device__ __forceinline__ u16 f2b(float f) {
    __hip_bfloat16 h = __float2bfloat16(f);   // RNE
    return __builtin_bit_cast(unsigned short, h);
}

// ---------------------------------------------------------------------------
// Convert all 6 weight tensors fp32 -> bf16 into one contiguous ws buffer.
// Order: wq | wk | wv | wo | w1 | w2  (each L-major contiguous as given).
// ---------------------------------------------------------------------------
#define WQ_SZ (6u * DM * DM)          // 1572864
#define W1_SZ (6u * DM * FF)          // 6291456
#define CVT_TOTAL (4u * WQ_SZ + 2u * W1_SZ)   // 18874368

__global__ __launch_bounds__(256) void cvt_kernel(
    const float* __restrict__ s0, const float* __restrict__ s1,
    const float* __restrict__ s2, const float* __restrict__ s3,
    const float* __restrict__ s4, const float* __restrict__ s5,
    u16* __restrict__ dst)
{
    size_t i8 = ((size_t)blockIdx.x * 256 + threadIdx.x) * 8;
    const float* src; size_t off;
    if      (i8 < 1u * WQ_SZ)            { src = s0; off = i8; }
    else if (i8 < 2u * WQ_SZ)            { src = s1; off = i8 - 1u * WQ_SZ; }
    else if (i8 < 3u * WQ_SZ)            { src = s2; off = i8 - 2u * WQ_SZ; }
    else if (i8 < 4u * WQ_SZ)            { src = s3; off = i8 - 3u * WQ_SZ; }
    else if (i8 < 4u * WQ_SZ + W1_SZ)    { src = s4; off = i8 - 4u * WQ_SZ; }
    else                                  { src = s5; off = i8 - (4u * WQ_SZ + W1_SZ); }
    u16x8 o;
#pragma unroll
    for (int j = 0; j < 8; j++) o[j] = f2b(src[off + j]);
    *(u16x8*)(dst + i8) = o;
}

// ---------------------------------------------------------------------------
// Embedding gather: fp32 master + bf16 shadow. One wave per row.
// ---------------------------------------------------------------------------
__global__ __launch_bounds__(256) void embed_kernel(
    const int* __restrict__ src, const float* __restrict__ emb,
    float* __restrict__ xf, u16* __restrict__ xb)
{
    int tid = threadIdx.x, lane = tid & 63, w = tid >> 6;
    int row = blockIdx.x * 4 + w;
    int id = src[row];
    const float* e = emb + (size_t)id * DM + lane * 8;
    float* xo = xf + (size_t)row * DM + lane * 8;
    u16x8 ob;
#pragma unroll
    for (int j = 0; j < 8; j++) {
        float v = e[j];
        xo[j] = v;
        ob[j] = f2b(v);
    }
    *(u16x8*)(xb + (size_t)row * DM + lane * 8) = ob;
}

// ---------------------------------------------------------------------------
// GEMM: C[M,N] = act(A[M,K] @ B[K,N] + bias[N]); A,B bf16, bias fp32.
// 64x64 tile / 256-thr block, 4 waves 2x2, each 32x32 via 2x2 mfma 16x16x32.
// ---------------------------------------------------------------------------
template <int ACT, bool OUT_F32>
__global__ __launch_bounds__(256) void gemm_kernel(
    const u16* __restrict__ A, const u16* __restrict__ B,
    const float* __restrict__ bias, void* __restrict__ Cv,
    int M, int N, int K)
{
    __shared__ u16 Al[64][40];   // [m][k], row stride 80 B (16B aligned)
    __shared__ u16 Bt[64][40];   // [n][k] (B transposed)

    int tid = threadIdx.x, lane = tid & 63, w = tid >> 6;
    int m0 = blockIdx.y * 64, n0 = blockIdx.x * 64;
    int wm = (w >> 1) * 32, wn = (w & 1) * 32;
    int mi = lane & 15, quad = lane >> 4, k8 = quad * 8;

    f32x4 zero4 = {0.f, 0.f, 0.f, 0.f};
    f32x4 acc[2][2];
#pragma unroll
    for (int i = 0; i < 2; i++)
#pragma unroll
        for (int j = 0; j < 2; j++) acc[i][j] = zero4;

    int arow = tid >> 2, aseg = tid & 3;      // A: 64 rows x 4 segs of 8
    int bk = tid >> 3, bn8 = (tid & 7) * 8;   // B: 32 k-rows x 8 segs of 8

    for (int kc = 0; kc < K; kc += 32) {
        u16x8 av = *(const u16x8*)(A + (size_t)(m0 + arow) * K + kc + aseg * 8);
        u16x8 bv = *(const u16x8*)(B + (size_t)(kc + bk) * N + n0 + bn8);
        __syncthreads();
        *(u16x8*)&Al[arow][aseg * 8] = av;
#pragma unroll
        for (int j = 0; j < 8; j++) Bt[bn8 + j][bk] = bv[j];
        __syncthreads();

        bf16x8 a0 = *(const bf16x8*)&Al[wm + mi][k8];
        bf16x8 a1 = *(const bf16x8*)&Al[wm + 16 + mi][k8];
        bf16x8 b0 = *(const bf16x8*)&Bt[wn + mi][k8];
        bf16x8 b1 = *(const bf16x8*)&Bt[wn + 16 + mi][k8];
        acc[0][0] = __builtin_amdgcn_mfma_f32_16x16x32_bf16(a0, b0, acc[0][0], 0, 0, 0);
        acc[0][1] = __builtin_amdgcn_mfma_f32_16x16x32_bf16(a0, b1, acc[0][1], 0, 0, 0);
        acc[1][0] = __builtin_amdgcn_mfma_f32_16x16x32_bf16(a1, b0, acc[1][0], 0, 0, 0);
        acc[1][1] = __builtin_amdgcn_mfma_f32_16x16x32_bf16(a1, b1, acc[1][1], 0, 0, 0);
    }

#pragma unroll
    for (int i = 0; i < 2; i++) {
#pragma unroll
        for (int j = 0; j < 2; j++) {
            int col = n0 + wn + j * 16 + mi;
            float bb = bias[col];
#pragma unroll
            for (int r = 0; r < 4; r++) {
                int row = m0 + wm + i * 16 + quad * 4 + r;
                float o = acc[i][j][r] + bb;
                if (ACT) o = fmaxf(o, 0.f);
                if (OUT_F32) ((float*)Cv)[(size_t)row * N + col] = o;
                else         ((u16*)Cv)[(size_t)row * N + col] = f2b(o);
            }
        }
    }
}

// ---------------------------------------------------------------------------
// Flash attention (causal). Block = (q-tile of 64, b*h). 4 waves x 16 q-rows.
// ---------------------------------------------------------------------------
__global__ __launch_bounds__(256) void attn_kernel(
    const u16* __restrict__ Q, const u16* __restrict__ K,
    const u16* __restrict__ V, u16* __restrict__ O)
{
    __shared__ u16 Kl[64][72];       // [key][d]
    __shared__ u16 Vt[64][72];       // [d][key]  (V transposed)
    __shared__ u16 Pl[4][16][72];    // per-wave P [qrow][key]

    int tid = threadIdx.x, lane = tid & 63, w = tid >> 6;
    int qt = blockIdx.x;
    int bh = blockIdx.y;
    int b = bh >> 3, h = bh & 7;
    int q0 = qt * 64;
    int mi = lane & 15, quad = lane >> 4, k8 = quad * 8;

    size_t base = ((size_t)b * S_LEN) * DM + h * 64;

    const u16* qrow = Q + base + (size_t)(q0 + w * 16 + mi) * DM;
    bf16x8 aq0 = *(const bf16x8*)(qrow + k8);        // d in [0,32)
    bf16x8 aq1 = *(const bf16x8*)(qrow + 32 + k8);   // d in [32,64)

    f32x4 zero4 = {0.f, 0.f, 0.f, 0.f};
    float mst[4], lst[4];
    f32x4 acc[4];
#pragma unroll
    for (int r = 0; r < 4; r++) { mst[r] = -__builtin_inff(); lst[r] = 0.f; }
#pragma unroll
    for (int g = 0; g < 4; g++) acc[g] = zero4;

    int srow = tid >> 2, sseg = tid & 3;

    for (int kt = 0; kt <= qt; kt++) {
        const u16* krow = K + base + (size_t)(kt * 64 + srow) * DM + sseg * 16;
        const u16* vrow = V + base + (size_t)(kt * 64 + srow) * DM + sseg * 16;
        u16x8 kv0 = *(const u16x8*)(krow);
        u16x8 kv1 = *(const u16x8*)(krow + 8);
        u16x8 vv0 = *(const u16x8*)(vrow);
        u16x8 vv1 = *(const u16x8*)(vrow + 8);
        __syncthreads();
        *(u16x8*)&Kl[srow][sseg * 16] = kv0;
        *(u16x8*)&Kl[srow][sseg * 16 + 8] = kv1;
#pragma unroll
        for (int j = 0; j < 8; j++) {
            Vt[sseg * 16 + j][srow] = vv0[j];
            Vt[sseg * 16 + 8 + j][srow] = vv1[j];
        }
        __syncthreads();

        // QK^T
        f32x4 sc[4];
#pragma unroll
        for (int g = 0; g < 4; g++) {
            bf16x8 b0 = *(const bf16x8*)&Kl[g * 16 + mi][k8];
            bf16x8 b1 = *(const bf16x8*)&Kl[g * 16 + mi][32 + k8];
            f32x4 s = __builtin_amdgcn_mfma_f32_16x16x32_bf16(aq0, b0, zero4, 0, 0, 0);
            s = __builtin_amdgcn_mfma_f32_16x16x32_bf16(aq1, b1, s, 0, 0, 0);
            sc[g] = s * 0.125f;   // 1/sqrt(64)
        }

        if (kt == qt) {   // causal mask on diagonal tile
            int qr = w * 16 + quad * 4;
#pragma unroll
            for (int g = 0; g < 4; g++) {
                int kcol = g * 16 + mi;
#pragma unroll
                for (int r = 0; r < 4; r++)
                    if (kcol > qr + r) sc[g][r] = -1e30f;
            }
        }

        // online softmax (row = quad*4 + r)
        float pr[4][4];
#pragma unroll
        for (int r = 0; r < 4; r++) {
            float rm = fmaxf(fmaxf(sc[0][r], sc[1][r]), fmaxf(sc[2][r], sc[3][r]));
#pragma unroll
            for (int d = 1; d < 16; d <<= 1) rm = fmaxf(rm, __shfl_xor(rm, d));
            float mnew = fmaxf(mst[r], rm);
            float alpha = __expf(mst[r] - mnew);
            float rs = 0.f;
#pragma unroll
            for (int g = 0; g < 4; g++) {
                pr[g][r] = __expf(sc[g][r] - mnew);
                rs += pr[g][r];
            }
#pragma unroll
            for (int d = 1; d < 16; d <<= 1) rs += __shfl_xor(rs, d);
            lst[r] = lst[r] * alpha + rs;
            mst[r] = mnew;
#pragma unroll
            for (int g = 0; g < 4; g++) acc[g][r] *= alpha;
        }

        // P -> LDS (C-layout write), re-read in A-layout
#pragma unroll
        for (int g = 0; g < 4; g++)
#pragma unroll
            for (int r = 0; r < 4; r++)
                Pl[w][quad * 4 + r][g * 16 + mi] = f2b(pr[g][r]);
        __syncthreads();

        // PV
#pragma unroll
        for (int kc2 = 0; kc2 < 2; kc2++) {
            bf16x8 ap = *(const bf16x8*)&Pl[w][mi][kc2 * 32 + k8];
#pragma unroll
            for (int g2 = 0; g2 < 4; g2++) {
                bf16x8 bv = *(const bf16x8*)&Vt[g2 * 16 + mi][kc2 * 32 + k8];
                acc[g2] = __builtin_amdgcn_mfma_f32_16x16x32_bf16(ap, bv, acc[g2], 0, 0, 0);
            }
        }
        __syncthreads();
    }

#pragma unroll
    for (int g2 = 0; g2 < 4; g2++)
#pragma unroll
        for (int r = 0; r < 4; r++) {
            float o = acc[g2][r] / lst[r];
            O[base + (size_t)(q0 + w * 16 + quad * 4 + r) * DM + g2 * 16 + mi] = f2b(o);
        }
}

// ---------------------------------------------------------------------------
// x = LN(x + delta); writes fp32 master + bf16 shadow. One wave per row.
// ---------------------------------------------------------------------------
__global__ __launch_bounds__(256) void add_ln_kernel(
    const float* __restrict__ X, const float* __restrict__ Dl,
    const float* __restrict__ G, const float* __restrict__ Bb,
    float* __restrict__ Xout, u16* __restrict__ Bout)
{
    int tid = threadIdx.x, lane = tid & 63, w = tid >> 6;
    int row = blockIdx.x * 4 + w;
    size_t off = (size_t)row * DM;

    float v[8];
    float s = 0.f;
#pragma unroll
    for (int j = 0; j < 8; j++) {
        int c = j * 64 + lane;
        v[j] = X[off + c] + Dl[off + c];
        s += v[j];
    }
#pragma unroll
    for (int d = 1; d < 64; d <<= 1) s += __shfl_xor(s, d);
    float mean = s * (1.f / 512.f);
    float vs = 0.f;
#pragma unroll
    for (int j = 0; j < 8; j++) { float t = v[j] - mean; vs += t * t; }
#pragma unroll
    for (int d = 1; d < 64; d <<= 1) vs += __shfl_xor(vs, d);
    float rstd = rsqrtf(vs * (1.f / 512.f) + 1e-5f);
#pragma unroll
    for (int j = 0; j < 8; j++) {
        int c = j * 64 + lane;
        float o = (v[j] - mean) * rstd * G[c] + Bb[c];
        Xout[off + c] = o;
        Bout[off + c] = f2b(o);
    }
}

// ---------------------------------------------------------------------------
extern "C" void kernel_launch(void* const* d_in, const int* in_sizes, int n_in,
                              void* d_out, int out_size, void* d_ws, size_t ws_size,
                              hipStream_t stream)
{
    const int*   src  = (const int*)d_in[0];
    const float* emb  = (const float*)d_in[1];
    const float* ln_g = (const float*)d_in[2];
    const float* ln_b = (const float*)d_in[3];
    const float* wq = (const float*)d_in[4];
    const float* bq = (const float*)d_in[5];
    const float* wk = (const float*)d_in[6];
    const float* bk = (const float*)d_in[7];
    const float* wv = (const float*)d_in[8];
    const float* bv = (const float*)d_in[9];
    const float* wo = (const float*)d_in[10];
    const float* bo = (const float*)d_in[11];
    const float* w1 = (const float*)d_in[12];
    const float* b1 = (const float*)d_in[13];
    const float* w2 = (const float*)d_in[14];
    const float* b2 = (const float*)d_in[15];

    // workspace layout (108 MB):
    //  [0,16)   xf   fp32 residual master
    //  [16,24)  xb   bf16 shadow
    //  [24,56)  qb/kb/vb/ab (8 MB each)  -- aliased by h1 (32 MB) in FFN phase
    //  [56,72)  dlt  fp32 delta
    //  [72,108) wbf  bf16 weights (wq|wk|wv|wo|w1|w2)
    char* ws = (char*)d_ws;
    float* xf  = (float*)(ws);
    u16*   xb  = (u16*)(ws + (16u << 20));
    u16*   qb  = (u16*)(ws + (24u << 20));
    u16*   kb  = (u16*)(ws + (32u << 20));
    u16*   vb  = (u16*)(ws + (40u << 20));
    u16*   ab  = (u16*)(ws + (48u << 20));
    u16*   h1  = (u16*)(ws + (24u << 20));   // aliases qb..ab
    float* dlt = (float*)(ws + (56u << 20));
    u16*   wbf = (u16*)(ws + (72u << 20));

    const int ROWS = 4 * S_LEN;   // 8192

    cvt_kernel<<<CVT_TOTAL / (256 * 8), 256, 0, stream>>>(wq, wk, wv, wo, w1, w2, wbf);
    embed_kernel<<<ROWS / 4, 256, 0, stream>>>(src, emb, xf, xb);

    dim3 g512(512 / 64, ROWS / 64);
    dim3 g2048(2048 / 64, ROWS / 64);
    dim3 gattn(S_LEN / 64, 4 * NHEAD);

    for (int l = 0; l < 6; l++) {
        const u16* Wq = wbf + 0u * WQ_SZ + (size_t)l * DM * DM;
        const u16* Wk = wbf + 1u * WQ_SZ + (size_t)l * DM * DM;
        const u16* Wv = wbf + 2u * WQ_SZ + (size_t)l * DM * DM;
        const u16* Wo = wbf + 3u * WQ_SZ + (size_t)l * DM * DM;
        const u16* W1 = wbf + 4u * WQ_SZ + (size_t)l * DM * FF;
        const u16* W2 = wbf + 4u * WQ_SZ + W1_SZ + (size_t)l * FF * DM;
        const float* Bq = bq + l * DM;
        const float* Bk = bk + l * DM;
        const float* Bv = bv + l * DM;
        const float* Bo = bo + l * DM;
        const float* B1 = b1 + l * FF;
        const float* B2 = b2 + l * DM;

        gemm_kernel<0, false><<<g512, 256, 0, stream>>>(xb, Wq, Bq, qb, ROWS, DM, DM);
        gemm_kernel<0, false><<<g512, 256, 0, stream>>>(xb, Wk, Bk, kb, ROWS, DM, DM);
        gemm_kernel<0, false><<<g512, 256, 0, stream>>>(xb, Wv, Bv, vb, ROWS, DM, DM);

        attn_kernel<<<gattn, 256, 0, stream>>>(qb, kb, vb, ab);

        gemm_kernel<0, true><<<g512, 256, 0, stream>>>(ab, Wo, Bo, dlt, ROWS, DM, DM);
        add_ln_kernel<<<ROWS / 4, 256, 0, stream>>>(xf, dlt, ln_g, ln_b, xf, xb);

        gemm_kernel<1, false><<<g2048, 256, 0, stream>>>(xb, W1, B1, h1, ROWS, FF, DM);
        gemm_kernel<1, true><<<g512, 256, 0, stream>>>(h1, W2, B2, dlt, ROWS, DM, FF);
        add_ln_kernel<<<ROWS / 4, 256, 0, stream>>>(xf, dlt, ln_g, ln_b,
                                                    (l == 5) ? (float*)d_out : xf, xb);
    }
}

// Round 3
// 1776.737 us; speedup vs baseline: 1.5574x; 1.5574x over previous
//
#include <hip/hip_runtime.h>
#include <hip/hip_bf16.h>

// ---------------------------------------------------------------------------
// Encoder: B=4, S=2048, V=32000, D=512, F=2048, L=6, H=8, Dh=64
// fp32 on the wire; bf16 MFMA GEMMs (m97 structure: 128x128 tile,
// global_load_lds width-16), fp32 accumulate, fp32 residual master.
// ---------------------------------------------------------------------------

typedef unsigned short u16;
typedef __bf16 bf16x8 __attribute__((ext_vector_type(8)));
typedef float f32x4 __attribute__((ext_vector_type(4)));
typedef unsigned short u16x8 __attribute__((ext_vector_type(8)));

#define S_LEN 2048
#define DM 512
#define FF 2048
#define NHEAD 8
#define QKV_STRIDE 1536

__device__ __forceinline__ u16 f2b(float f) {
    __hip_bfloat16 h = __float2bfloat16(f);   // RNE
    return __builtin_bit_cast(unsigned short, h);
}

typedef const __attribute__((address_space(1))) unsigned int glb_u32;
typedef __attribute__((address_space(3))) unsigned int lds_u32;

__device__ __forceinline__ void async16(const u16* g, u16* l) {
    __builtin_amdgcn_global_load_lds((glb_u32*)g, (lds_u32*)l, 16, 0, 0);
}

// ---------------------------------------------------------------------------
// Transpose+convert: Wt[n][k] (bf16) = W[k][n] (fp32), per layer.
// dst row index gets rowOff added (for packing wq/wk/wv into one [1536][512]).
// ---------------------------------------------------------------------------
__global__ __launch_bounds__(256) void transp_kernel(
    const float* __restrict__ W, u16* __restrict__ Wt,
    int K, int N, size_t layerStride, int rowOff)
{
    __shared__ float tile[64][65];
    int l = blockIdx.z;
    const float* src = W + (size_t)l * K * N;
    u16* dst = Wt + (size_t)l * layerStride;
    int k0 = blockIdx.y * 64, n0 = blockIdx.x * 64;
    int tid = threadIdx.x;

#pragma unroll
    for (int i = 0; i < 4; i++) {
        int r = (tid >> 4) + i * 16;          // k-local 0..63
        int c4 = (tid & 15) * 4;              // n-local
        float4 v = *(const float4*)&src[(size_t)(k0 + r) * N + n0 + c4];
        tile[r][c4 + 0] = v.x; tile[r][c4 + 1] = v.y;
        tile[r][c4 + 2] = v.z; tile[r][c4 + 3] = v.w;
    }
    __syncthreads();
#pragma unroll
    for (int it = 0; it < 2; it++) {
        int idx = it * 256 + tid;
        int n = idx >> 3, seg = (idx & 7) * 8;   // n-local, k-local seg
        u16x8 o;
#pragma unroll
        for (int t = 0; t < 8; t++) o[t] = f2b(tile[seg + t][n]);
        *(u16x8*)&dst[(size_t)(rowOff + n0 + n) * K + k0 + seg] = o;
    }
}

// ---------------------------------------------------------------------------
// Embedding gather: fp32 master + bf16 shadow. One wave per row.
// ---------------------------------------------------------------------------
__global__ __launch_bounds__(256) void embed_kernel(
    const int* __restrict__ src, const float* __restrict__ emb,
    float* __restrict__ xf, u16* __restrict__ xb)
{
    int tid = threadIdx.x, lane = tid & 63, w = tid >> 6;
    int row = blockIdx.x * 4 + w;
    int id = src[row];
    const float* e = emb + (size_t)id * DM + lane * 8;
    float* xo = xf + (size_t)row * DM + lane * 8;
    u16x8 ob;
#pragma unroll
    for (int j = 0; j < 8; j++) {
        float v = e[j];
        xo[j] = v;
        ob[j] = f2b(v);
    }
    *(u16x8*)(xb + (size_t)row * DM + lane * 8) = ob;
}

// ---------------------------------------------------------------------------
// GEMM (m97 structure): C[M,N] = act(A[M,K] @ Bt[N,K]^T + bias)
// 128x128 tile / 256 thr, 4 waves 2x2 of 64x64, BK=32, global_load_lds x16.
// bias selected from 4 pointers by col>>9 (QKV fusion / long-N support).
// ---------------------------------------------------------------------------
template <int ACT, bool OUT_F32>
__global__ __launch_bounds__(256) void gemm_kernel(
    const u16* __restrict__ A, const u16* __restrict__ Bt,
    const float* __restrict__ bias0, const float* __restrict__ bias1,
    const float* __restrict__ bias2, const float* __restrict__ bias3,
    void* __restrict__ Cv, int N, int K)
{
    __shared__ __align__(16) u16 As[128 * 32];
    __shared__ __align__(16) u16 Bs[128 * 32];

    int tid = threadIdx.x, lane = tid & 63, w = tid >> 6;
    int m0 = blockIdx.y * 128, n0 = blockIdx.x * 128;
    int wm = (w >> 1) * 64, wn = (w & 1) * 64;
    int mi = lane & 15, quad = lane >> 4, k8 = quad * 8;

    f32x4 acc[4][4];
#pragma unroll
    for (int i = 0; i < 4; i++)
#pragma unroll
        for (int j = 0; j < 4; j++) acc[i][j] = (f32x4){0.f, 0.f, 0.f, 0.f};

    // staging: chunk idx = c*256 + tid ; row = idx>>2, seg = (idx&3)*8
    int r0 = tid >> 2, s0 = (tid & 3) * 8;
    const u16* Ag0 = A + (size_t)(m0 + r0) * K + s0;
    const u16* Ag1 = A + (size_t)(m0 + 64 + r0) * K + s0;
    const u16* Bg0 = Bt + (size_t)(n0 + r0) * K + s0;
    const u16* Bg1 = Bt + (size_t)(n0 + 64 + r0) * K + s0;
    u16* Al0 = As + (size_t)(w * 64) * 8;          // wave-uniform LDS bases
    u16* Al1 = As + (size_t)(256 + w * 64) * 8;
    u16* Bl0 = Bs + (size_t)(w * 64) * 8;
    u16* Bl1 = Bs + (size_t)(256 + w * 64) * 8;

    for (int kc = 0; kc < K; kc += 32) {
        __syncthreads();
        async16(Ag0 + kc, Al0);
        async16(Ag1 + kc, Al1);
        async16(Bg0 + kc, Bl0);
        async16(Bg1 + kc, Bl1);
        __syncthreads();

        bf16x8 af[4], bfr[4];
#pragma unroll
        for (int i = 0; i < 4; i++)
            af[i] = *(const bf16x8*)&As[(size_t)(wm + i * 16 + mi) * 32 + k8];
#pragma unroll
        for (int j = 0; j < 4; j++)
            bfr[j] = *(const bf16x8*)&Bs[(size_t)(wn + j * 16 + mi) * 32 + k8];
#pragma unroll
        for (int i = 0; i < 4; i++)
#pragma unroll
            for (int j = 0; j < 4; j++)
                acc[i][j] = __builtin_amdgcn_mfma_f32_16x16x32_bf16(
                    af[i], bfr[j], acc[i][j], 0, 0, 0);
    }

#pragma unroll
    for (int j = 0; j < 4; j++) {
        int col = n0 + wn + j * 16 + mi;
        int bi = col >> 9;   // lane-uniform within a j-group
        const float* bp = (bi == 0) ? bias0 : (bi == 1) ? bias1
                        : (bi == 2) ? bias2 : bias3;
        float bb = bp[col & 511];
#pragma unroll
        for (int i = 0; i < 4; i++) {
#pragma unroll
            for (int r = 0; r < 4; r++) {
                int row = m0 + wm + i * 16 + quad * 4 + r;
                float o = acc[i][j][r] + bb;
                if (ACT) o = fmaxf(o, 0.f);
                if (OUT_F32) ((float*)Cv)[(size_t)row * N + col] = o;
                else         ((u16*)Cv)[(size_t)row * N + col] = f2b(o);
            }
        }
    }
}

// ---------------------------------------------------------------------------
// Flash attention (causal), fused-QKV input (row stride 1536).
// Block = (64-row q-tile, b*h). 4 waves x 16 q-rows. K/V prefetched into
// registers one tile ahead; Vt stored XOR-swizzled to kill bank conflicts;
// 2 barriers per tile (Pl is wave-private).
// ---------------------------------------------------------------------------
__global__ __launch_bounds__(256) void attn_kernel(
    const u16* __restrict__ qkv, u16* __restrict__ O)
{
    __shared__ __align__(16) u16 Kl[64][72];     // [key][d]
    __shared__ __align__(16) u16 Vt[64][72];     // [d][key^swizzle]
    __shared__ __align__(16) u16 Pl[4][16][72];  // per-wave P

    int tid = threadIdx.x, lane = tid & 63, w = tid >> 6;
    int qt = blockIdx.x;
    int bh = blockIdx.y;
    int b = bh >> 3, h = bh & 7;
    int q0 = qt * 64;
    int mi = lane & 15, quad = lane >> 4, k8 = quad * 8;

    size_t qbase = ((size_t)b * S_LEN) * QKV_STRIDE + h * 64;
    const u16* Qp = qkv + qbase;
    const u16* Kp = qkv + qbase + 512;
    const u16* Vp = qkv + qbase + 1024;
    size_t obase = ((size_t)b * S_LEN) * DM + h * 64;

    const u16* qrow = Qp + (size_t)(q0 + w * 16 + mi) * QKV_STRIDE;
    bf16x8 aq0 = *(const bf16x8*)(qrow + k8);
    bf16x8 aq1 = *(const bf16x8*)(qrow + 32 + k8);

    f32x4 zero4 = {0.f, 0.f, 0.f, 0.f};
    float mst[4], lst[4];
    f32x4 acc[4];
#pragma unroll
    for (int r = 0; r < 4; r++) { mst[r] = -__builtin_inff(); lst[r] = 0.f; }
#pragma unroll
    for (int g = 0; g < 4; g++) acc[g] = zero4;

    int srow = tid >> 2, sseg = tid & 3;
    int vcol = srow ^ (sseg * 8);   // XOR-swizzled Vt column

    // prefetch tile 0
    const u16* krow = Kp + (size_t)srow * QKV_STRIDE + sseg * 16;
    const u16* vrow = Vp + (size_t)srow * QKV_STRIDE + sseg * 16;
    u16x8 kv0 = *(const u16x8*)(krow);
    u16x8 kv1 = *(const u16x8*)(krow + 8);
    u16x8 vv0 = *(const u16x8*)(vrow);
    u16x8 vv1 = *(const u16x8*)(vrow + 8);

    for (int kt = 0; kt <= qt; kt++) {
        __syncthreads();   // all waves done reading LDS of prev tile
        *(u16x8*)&Kl[srow][sseg * 16] = kv0;
        *(u16x8*)&Kl[srow][sseg * 16 + 8] = kv1;
#pragma unroll
        for (int j = 0; j < 8; j++) {
            Vt[sseg * 16 + j][vcol] = vv0[j];
            Vt[sseg * 16 + 8 + j][vcol] = vv1[j];
        }
        __syncthreads();

        if (kt < qt) {   // prefetch next tile while computing this one
            const u16* krn = Kp + (size_t)((kt + 1) * 64 + srow) * QKV_STRIDE + sseg * 16;
            const u16* vrn = Vp + (size_t)((kt + 1) * 64 + srow) * QKV_STRIDE + sseg * 16;
            kv0 = *(const u16x8*)(krn);
            kv1 = *(const u16x8*)(krn + 8);
            vv0 = *(const u16x8*)(vrn);
            vv1 = *(const u16x8*)(vrn + 8);
        }

        // QK^T
        f32x4 sc[4];
#pragma unroll
        for (int g = 0; g < 4; g++) {
            bf16x8 b0 = *(const bf16x8*)&Kl[g * 16 + mi][k8];
            bf16x8 b1 = *(const bf16x8*)&Kl[g * 16 + mi][32 + k8];
            f32x4 s = __builtin_amdgcn_mfma_f32_16x16x32_bf16(aq0, b0, zero4, 0, 0, 0);
            s = __builtin_amdgcn_mfma_f32_16x16x32_bf16(aq1, b1, s, 0, 0, 0);
            sc[g] = s * 0.125f;   // 1/sqrt(64)
        }

        if (kt == qt) {   // causal mask on diagonal tile
            int qr = w * 16 + quad * 4;
#pragma unroll
            for (int g = 0; g < 4; g++) {
                int kcol = g * 16 + mi;
#pragma unroll
                for (int r = 0; r < 4; r++)
                    if (kcol > qr + r) sc[g][r] = -1e30f;
            }
        }

        // online softmax (row = quad*4 + r)
        float pr[4][4];
#pragma unroll
        for (int r = 0; r < 4; r++) {
            float rm = fmaxf(fmaxf(sc[0][r], sc[1][r]), fmaxf(sc[2][r], sc[3][r]));
#pragma unroll
            for (int d = 1; d < 16; d <<= 1) rm = fmaxf(rm, __shfl_xor(rm, d));
            float mnew = fmaxf(mst[r], rm);
            float alpha = __expf(mst[r] - mnew);
            float rs = 0.f;
#pragma unroll
            for (int g = 0; g < 4; g++) {
                pr[g][r] = __expf(sc[g][r] - mnew);
                rs += pr[g][r];
            }
#pragma unroll
            for (int d = 1; d < 16; d <<= 1) rs += __shfl_xor(rs, d);
            lst[r] = lst[r] * alpha + rs;
            mst[r] = mnew;
#pragma unroll
            for (int g = 0; g < 4; g++) acc[g][r] *= alpha;
        }

        // P -> LDS (wave-private, no barrier needed)
#pragma unroll
        for (int g = 0; g < 4; g++)
#pragma unroll
            for (int r = 0; r < 4; r++)
                Pl[w][quad * 4 + r][g * 16 + mi] = f2b(pr[g][r]);

        // PV (Vt read with un-swizzle: group = quad ^ g2)
#pragma unroll
        for (int kc2 = 0; kc2 < 2; kc2++) {
            bf16x8 ap = *(const bf16x8*)&Pl[w][mi][kc2 * 32 + k8];
#pragma unroll
            for (int g2 = 0; g2 < 4; g2++) {
                bf16x8 bv = *(const bf16x8*)&Vt[g2 * 16 + mi][kc2 * 32 + ((quad ^ g2) * 8)];
                acc[g2] = __builtin_amdgcn_mfma_f32_16x16x32_bf16(ap, bv, acc[g2], 0, 0, 0);
            }
        }
    }

#pragma unroll
    for (int g2 = 0; g2 < 4; g2++)
#pragma unroll
        for (int r = 0; r < 4; r++) {
            float o = acc[g2][r] / lst[r];
            O[obase + (size_t)(q0 + w * 16 + quad * 4 + r) * DM + g2 * 16 + mi] = f2b(o);
        }
}

// ---------------------------------------------------------------------------
// x = LN(x + delta); writes fp32 master + bf16 shadow. One wave per row.
// ---------------------------------------------------------------------------
__global__ __launch_bounds__(256) void add_ln_kernel(
    const float* __restrict__ X, const float* __restrict__ Dl,
    const float* __restrict__ G, const float* __restrict__ Bb,
    float* __restrict__ Xout, u16* __restrict__ Bout)
{
    int tid = threadIdx.x, lane = tid & 63, w = tid >> 6;
    int row = blockIdx.x * 4 + w;
    size_t off = (size_t)row * DM;

    float v[8];
    float s = 0.f;
#pragma unroll
    for (int j = 0; j < 8; j++) {
        int c = j * 64 + lane;
        v[j] = X[off + c] + Dl[off + c];
        s += v[j];
    }
#pragma unroll
    for (int d = 1; d < 64; d <<= 1) s += __shfl_xor(s, d);
    float mean = s * (1.f / 512.f);
    float vs = 0.f;
#pragma unroll
    for (int j = 0; j < 8; j++) { float t = v[j] - mean; vs += t * t; }
#pragma unroll
    for (int d = 1; d < 64; d <<= 1) vs += __shfl_xor(vs, d);
    float rstd = rsqrtf(vs * (1.f / 512.f) + 1e-5f);
#pragma unroll
    for (int j = 0; j < 8; j++) {
        int c = j * 64 + lane;
        float o = (v[j] - mean) * rstd * G[c] + Bb[c];
        Xout[off + c] = o;
        Bout[off + c] = f2b(o);
    }
}

// ---------------------------------------------------------------------------
extern "C" void kernel_launch(void* const* d_in, const int* in_sizes, int n_in,
                              void* d_out, int out_size, void* d_ws, size_t ws_size,
                              hipStream_t stream)
{
    const int*   src  = (const int*)d_in[0];
    const float* emb  = (const float*)d_in[1];
    const float* ln_g = (const float*)d_in[2];
    const float* ln_b = (const float*)d_in[3];
    const float* wq = (const float*)d_in[4];
    const float* bq = (const float*)d_in[5];
    const float* wk = (const float*)d_in[6];
    const float* bk = (const float*)d_in[7];
    const float* wv = (const float*)d_in[8];
    const float* bv = (const float*)d_in[9];
    const float* wo = (const float*)d_in[10];
    const float* bo = (const float*)d_in[11];
    const float* w1 = (const float*)d_in[12];
    const float* b1 = (const float*)d_in[13];
    const float* w2 = (const float*)d_in[14];
    const float* b2 = (const float*)d_in[15];

    // ws layout (108 MB):
    //  [0,16)   xf fp32 residual | [16,24) xb bf16 shadow
    //  [24,48)  qkv bf16 [8192][1536]   (aliased by h1 in FFN phase)
    //  [48,56)  ab bf16 [8192][512]
    //  [56,72)  dlt fp32
    //  [72,108) wbf: qkv_t | wo_t | w1_t | w2_t  (bf16, [N][K] transposed)
    char* ws = (char*)d_ws;
    float* xf  = (float*)(ws);
    u16*   xb  = (u16*)(ws + (16u << 20));
    u16*   qkv = (u16*)(ws + (24u << 20));
    u16*   ab  = (u16*)(ws + (48u << 20));
    u16*   h1  = (u16*)(ws + (24u << 20));   // aliases qkv+ab
    float* dlt = (float*)(ws + (56u << 20));
    u16*   wbf = (u16*)(ws + (72u << 20));

    u16* qkvt = wbf;                              // [L][1536][512]
    u16* wot  = wbf + 6u * 1536 * 512;            // [L][512][512]
    u16* w1t  = wot + 6u * 512 * 512;             // [L][2048][512]
    u16* w2t  = w1t + 6u * 512 * 2048;            // [L][512][2048]

    const int ROWS = 4 * S_LEN;   // 8192

    // transpose+convert weights (per launch; ws is re-poisoned each call)
    transp_kernel<<<dim3(8, 8, 6),  256, 0, stream>>>(wq, qkvt, 512, 512, 1536u * 512, 0);
    transp_kernel<<<dim3(8, 8, 6),  256, 0, stream>>>(wk, qkvt, 512, 512, 1536u * 512, 512);
    transp_kernel<<<dim3(8, 8, 6),  256, 0, stream>>>(wv, qkvt, 512, 512, 1536u * 512, 1024);
    transp_kernel<<<dim3(8, 8, 6),  256, 0, stream>>>(wo, wot, 512, 512, 512u * 512, 0);
    transp_kernel<<<dim3(32, 8, 6), 256, 0, stream>>>(w1, w1t, 512, 2048, 2048u * 512, 0);
    transp_kernel<<<dim3(8, 32, 6), 256, 0, stream>>>(w2, w2t, 2048, 512, 512u * 2048, 0);

    embed_kernel<<<ROWS / 4, 256, 0, stream>>>(src, emb, xf, xb);

    dim3 gqkv(1536 / 128, ROWS / 128);
    dim3 g512(512 / 128, ROWS / 128);
    dim3 g2048(2048 / 128, ROWS / 128);
    dim3 gattn(S_LEN / 64, 4 * NHEAD);

    for (int l = 0; l < 6; l++) {
        const u16* Wqkv = qkvt + (size_t)l * 1536 * 512;
        const u16* Wo   = wot + (size_t)l * 512 * 512;
        const u16* W1   = w1t + (size_t)l * 2048 * 512;
        const u16* W2   = w2t + (size_t)l * 512 * 2048;
        const float* Bq = bq + l * DM;
        const float* Bk = bk + l * DM;
        const float* Bv = bv + l * DM;
        const float* Bo = bo + l * DM;
        const float* B1 = b1 + l * FF;
        const float* B2 = b2 + l * DM;

        gemm_kernel<0, false><<<gqkv, 256, 0, stream>>>(
            xb, Wqkv, Bq, Bk, Bv, Bv, qkv, QKV_STRIDE, 512);

        attn_kernel<<<gattn, 256, 0, stream>>>(qkv, ab);

        gemm_kernel<0, true><<<g512, 256, 0, stream>>>(
            ab, Wo, Bo, Bo, Bo, Bo, dlt, 512, 512);
        add_ln_kernel<<<ROWS / 4, 256, 0, stream>>>(xf, dlt, ln_g, ln_b, xf, xb);

        gemm_kernel<1, false><<<g2048, 256, 0, stream>>>(
            xb, W1, B1, B1 + 512, B1 + 1024, B1 + 1536, h1, FF, 512);
        gemm_kernel<1, true><<<g512, 256, 0, stream>>>(
            h1, W2, B2, B2, B2, B2, dlt, 512, 2048);
        add_ln_kernel<<<ROWS / 4, 256, 0, stream>>>(xf, dlt, ln_g, ln_b,
                                                    (l == 5) ? (float*)d_out : xf, xb);
    }
}

// Round 4
// 1434.016 us; speedup vs baseline: 1.9296x; 1.2390x over previous
//
#include <hip/hip_runtime.h>
#include <hip/hip_bf16.h>

// ---------------------------------------------------------------------------
// Encoder: B=4, S=2048, V=32000, D=512, F=2048, L=6, H=8, Dh=64
// fp32 on the wire; bf16 MFMA GEMMs (m97 structure), fp32 residual master.
// ---------------------------------------------------------------------------

typedef unsigned short u16;
typedef __bf16 bf16x8 __attribute__((ext_vector_type(8)));
typedef float f32x4 __attribute__((ext_vector_type(4)));
typedef unsigned short u16x8 __attribute__((ext_vector_type(8)));

#define S_LEN 2048
#define DM 512
#define FF 2048
#define NHEAD 8
#define QKV_STRIDE 1536

__device__ __forceinline__ u16 f2b(float f) {
    __hip_bfloat16 h = __float2bfloat16(f);   // RNE
    return __builtin_bit_cast(unsigned short, h);
}

typedef const __attribute__((address_space(1))) unsigned int glb_u32;
typedef __attribute__((address_space(3))) unsigned int lds_u32;

__device__ __forceinline__ void async16(const u16* g, u16* l) {
    __builtin_amdgcn_global_load_lds((glb_u32*)g, (lds_u32*)l, 16, 0, 0);
}

// ---------------------------------------------------------------------------
// Transpose+convert: Wt[n][k] (bf16) = W[k][n] (fp32), per layer.
// ---------------------------------------------------------------------------
__global__ __launch_bounds__(256) void transp_kernel(
    const float* __restrict__ W, u16* __restrict__ Wt,
    int K, int N, size_t layerStride, int rowOff)
{
    __shared__ float tile[64][65];
    int l = blockIdx.z;
    const float* src = W + (size_t)l * K * N;
    u16* dst = Wt + (size_t)l * layerStride;
    int k0 = blockIdx.y * 64, n0 = blockIdx.x * 64;
    int tid = threadIdx.x;

#pragma unroll
    for (int i = 0; i < 4; i++) {
        int r = (tid >> 4) + i * 16;
        int c4 = (tid & 15) * 4;
        float4 v = *(const float4*)&src[(size_t)(k0 + r) * N + n0 + c4];
        tile[r][c4 + 0] = v.x; tile[r][c4 + 1] = v.y;
        tile[r][c4 + 2] = v.z; tile[r][c4 + 3] = v.w;
    }
    __syncthreads();
#pragma unroll
    for (int it = 0; it < 2; it++) {
        int idx = it * 256 + tid;
        int n = idx >> 3, seg = (idx & 7) * 8;
        u16x8 o;
#pragma unroll
        for (int t = 0; t < 8; t++) o[t] = f2b(tile[seg + t][n]);
        *(u16x8*)&dst[(size_t)(rowOff + n0 + n) * K + k0 + seg] = o;
    }
}

// ---------------------------------------------------------------------------
// Embedding gather: fp32 master + bf16 shadow. One wave per row.
// ---------------------------------------------------------------------------
__global__ __launch_bounds__(256) void embed_kernel(
    const int* __restrict__ src, const float* __restrict__ emb,
    float* __restrict__ xf, u16* __restrict__ xb)
{
    int tid = threadIdx.x, lane = tid & 63, w = tid >> 6;
    int row = blockIdx.x * 4 + w;
    int id = src[row];
    const float* e = emb + (size_t)id * DM + lane * 8;
    float* xo = xf + (size_t)row * DM + lane * 8;
    u16x8 ob;
#pragma unroll
    for (int j = 0; j < 8; j++) {
        float v = e[j];
        xo[j] = v;
        ob[j] = f2b(v);
    }
    *(u16x8*)(xb + (size_t)row * DM + lane * 8) = ob;
}

// ---------------------------------------------------------------------------
// GEMM (m97 structure): C[M,N] = act(A[M,K] @ Bt[N,K]^T + bias)
// 128xNT tile / 256 thr (NT=128 or 64), BK=32, global_load_lds width-16.
// ---------------------------------------------------------------------------
template <int ACT, bool OUT_F32, int NT>
__global__ __launch_bounds__(256) void gemm_kernel(
    const u16* __restrict__ A, const u16* __restrict__ Bt,
    const float* __restrict__ bias0, const float* __restrict__ bias1,
    const float* __restrict__ bias2, const float* __restrict__ bias3,
    void* __restrict__ Cv, int N, int K)
{
    constexpr int WN = NT / 2;      // wave n-extent: 64 or 32
    constexpr int JT = WN / 16;     // 4 or 2
    __shared__ __align__(16) u16 As[128 * 32];
    __shared__ __align__(16) u16 Bs[NT * 32];

    int tid = threadIdx.x, lane = tid & 63, w = tid >> 6;
    int m0 = blockIdx.y * 128, n0 = blockIdx.x * NT;
    int wm = (w >> 1) * 64, wn = (w & 1) * WN;
    int mi = lane & 15, quad = lane >> 4, k8 = quad * 8;

    f32x4 acc[4][JT];
#pragma unroll
    for (int i = 0; i < 4; i++)
#pragma unroll
        for (int j = 0; j < JT; j++) acc[i][j] = (f32x4){0.f, 0.f, 0.f, 0.f};

    int r0 = tid >> 2, s0 = (tid & 3) * 8;
    const u16* Ag0 = A + (size_t)(m0 + r0) * K + s0;
    const u16* Ag1 = A + (size_t)(m0 + 64 + r0) * K + s0;
    const u16* Bg0 = Bt + (size_t)(n0 + r0) * K + s0;
    const u16* Bg1 = Bt + (size_t)(n0 + 64 + r0) * K + s0;   // unused if NT==64
    u16* Al0 = As + (size_t)(w * 64) * 8;
    u16* Al1 = As + (size_t)(256 + w * 64) * 8;
    u16* Bl0 = Bs + (size_t)(w * 64) * 8;
    u16* Bl1 = Bs + (size_t)(256 + w * 64) * 8;

    for (int kc = 0; kc < K; kc += 32) {
        __syncthreads();
        async16(Ag0 + kc, Al0);
        async16(Ag1 + kc, Al1);
        async16(Bg0 + kc, Bl0);
        if (NT == 128) async16(Bg1 + kc, Bl1);
        __syncthreads();

        bf16x8 af[4], bfr[JT];
#pragma unroll
        for (int i = 0; i < 4; i++)
            af[i] = *(const bf16x8*)&As[(size_t)(wm + i * 16 + mi) * 32 + k8];
#pragma unroll
        for (int j = 0; j < JT; j++)
            bfr[j] = *(const bf16x8*)&Bs[(size_t)(wn + j * 16 + mi) * 32 + k8];
#pragma unroll
        for (int i = 0; i < 4; i++)
#pragma unroll
            for (int j = 0; j < JT; j++)
                acc[i][j] = __builtin_amdgcn_mfma_f32_16x16x32_bf16(
                    af[i], bfr[j], acc[i][j], 0, 0, 0);
    }

#pragma unroll
    for (int j = 0; j < JT; j++) {
        int col = n0 + wn + j * 16 + mi;
        int bi = col >> 9;
        const float* bp = (bi == 0) ? bias0 : (bi == 1) ? bias1
                        : (bi == 2) ? bias2 : bias3;
        float bb = bp[col & 511];
#pragma unroll
        for (int i = 0; i < 4; i++) {
#pragma unroll
            for (int r = 0; r < 4; r++) {
                int row = m0 + wm + i * 16 + quad * 4 + r;
                float o = acc[i][j][r] + bb;
                if (ACT) o = fmaxf(o, 0.f);
                if (OUT_F32) ((float*)Cv)[(size_t)row * N + col] = o;
                else         ((u16*)Cv)[(size_t)row * N + col] = f2b(o);
            }
        }
    }
}

// ---------------------------------------------------------------------------
// Flash attention (causal), fused-QKV input. Load-balanced: block x handles
// q-tiles x and 31-x (33 tile-iters each, uniform). 4 waves x 16 q-rows.
// K/V register-prefetched one tile ahead (carried across the phase switch);
// Vt XOR-swizzled; 2 barriers/tile.
// ---------------------------------------------------------------------------
__global__ __launch_bounds__(256) void attn_kernel(
    const u16* __restrict__ qkv, u16* __restrict__ O)
{
    __shared__ __align__(16) u16 Kl[64][72];
    __shared__ __align__(16) u16 Vt[64][72];
    __shared__ __align__(16) u16 Pl[4][16][72];

    int tid = threadIdx.x, lane = tid & 63, w = tid >> 6;
    int qA = blockIdx.x;          // 0..15
    int bh = blockIdx.y;
    int b = bh >> 3, h = bh & 7;
    int mi = lane & 15, quad = lane >> 4, k8 = quad * 8;

    size_t qbase = ((size_t)b * S_LEN) * QKV_STRIDE + h * 64;
    const u16* Qp = qkv + qbase;
    const u16* Kp = qkv + qbase + 512;
    const u16* Vp = qkv + qbase + 1024;
    size_t obase = ((size_t)b * S_LEN) * DM + h * 64;

    int srow = tid >> 2, sseg = tid & 3;
    int vcol = srow ^ (sseg * 8);

    f32x4 zero4 = {0.f, 0.f, 0.f, 0.f};

    // prefetch tile 0
    const u16* krow = Kp + (size_t)srow * QKV_STRIDE + sseg * 16;
    const u16* vrow = Vp + (size_t)srow * QKV_STRIDE + sseg * 16;
    u16x8 kv0 = *(const u16x8*)(krow);
    u16x8 kv1 = *(const u16x8*)(krow + 8);
    u16x8 vv0 = *(const u16x8*)(vrow);
    u16x8 vv1 = *(const u16x8*)(vrow + 8);

    for (int ph = 0; ph < 2; ph++) {
        int qt = ph ? (31 - qA) : qA;
        int q0 = qt * 64;

        const u16* qrow = Qp + (size_t)(q0 + w * 16 + mi) * QKV_STRIDE;
        bf16x8 aq0 = *(const bf16x8*)(qrow + k8);
        bf16x8 aq1 = *(const bf16x8*)(qrow + 32 + k8);

        float mst[4], lst[4];
        f32x4 acc[4];
#pragma unroll
        for (int r = 0; r < 4; r++) { mst[r] = -__builtin_inff(); lst[r] = 0.f; }
#pragma unroll
        for (int g = 0; g < 4; g++) acc[g] = zero4;

        for (int kt = 0; kt <= qt; kt++) {
            __syncthreads();
            *(u16x8*)&Kl[srow][sseg * 16] = kv0;
            *(u16x8*)&Kl[srow][sseg * 16 + 8] = kv1;
#pragma unroll
            for (int j = 0; j < 8; j++) {
                Vt[sseg * 16 + j][vcol] = vv0[j];
                Vt[sseg * 16 + 8 + j][vcol] = vv1[j];
            }
            __syncthreads();

            // prefetch next tile (kt+1, or tile 0 for the next phase)
            {
                int nkt = (kt < qt) ? kt + 1 : 0;
                const u16* krn = Kp + (size_t)(nkt * 64 + srow) * QKV_STRIDE + sseg * 16;
                const u16* vrn = Vp + (size_t)(nkt * 64 + srow) * QKV_STRIDE + sseg * 16;
                kv0 = *(const u16x8*)(krn);
                kv1 = *(const u16x8*)(krn + 8);
                vv0 = *(const u16x8*)(vrn);
                vv1 = *(const u16x8*)(vrn + 8);
            }

            // QK^T
            f32x4 sc[4];
#pragma unroll
            for (int g = 0; g < 4; g++) {
                bf16x8 b0 = *(const bf16x8*)&Kl[g * 16 + mi][k8];
                bf16x8 b1 = *(const bf16x8*)&Kl[g * 16 + mi][32 + k8];
                f32x4 s = __builtin_amdgcn_mfma_f32_16x16x32_bf16(aq0, b0, zero4, 0, 0, 0);
                s = __builtin_amdgcn_mfma_f32_16x16x32_bf16(aq1, b1, s, 0, 0, 0);
                sc[g] = s * 0.125f;   // 1/sqrt(64)
            }

            if (kt == qt) {   // causal mask on diagonal tile
                int qr = w * 16 + quad * 4;
#pragma unroll
                for (int g = 0; g < 4; g++) {
                    int kcol = g * 16 + mi;
#pragma unroll
                    for (int r = 0; r < 4; r++)
                        if (kcol > qr + r) sc[g][r] = -1e30f;
                }
            }

            // online softmax (row = quad*4 + r)
            float pr[4][4];
#pragma unroll
            for (int r = 0; r < 4; r++) {
                float rm = fmaxf(fmaxf(sc[0][r], sc[1][r]), fmaxf(sc[2][r], sc[3][r]));
#pragma unroll
                for (int d = 1; d < 16; d <<= 1) rm = fmaxf(rm, __shfl_xor(rm, d));
                float mnew = fmaxf(mst[r], rm);
                float alpha = __expf(mst[r] - mnew);
                float rs = 0.f;
#pragma unroll
                for (int g = 0; g < 4; g++) {
                    pr[g][r] = __expf(sc[g][r] - mnew);
                    rs += pr[g][r];
                }
#pragma unroll
                for (int d = 1; d < 16; d <<= 1) rs += __shfl_xor(rs, d);
                lst[r] = lst[r] * alpha + rs;
                mst[r] = mnew;
#pragma unroll
                for (int g = 0; g < 4; g++) acc[g][r] *= alpha;
            }

            // P -> LDS (wave-private)
#pragma unroll
            for (int g = 0; g < 4; g++)
#pragma unroll
                for (int r = 0; r < 4; r++)
                    Pl[w][quad * 4 + r][g * 16 + mi] = f2b(pr[g][r]);

            // PV (Vt read with un-swizzle)
#pragma unroll
            for (int kc2 = 0; kc2 < 2; kc2++) {
                bf16x8 ap = *(const bf16x8*)&Pl[w][mi][kc2 * 32 + k8];
#pragma unroll
                for (int g2 = 0; g2 < 4; g2++) {
                    bf16x8 bv = *(const bf16x8*)&Vt[g2 * 16 + mi][kc2 * 32 + ((quad ^ g2) * 8)];
                    acc[g2] = __builtin_amdgcn_mfma_f32_16x16x32_bf16(ap, bv, acc[g2], 0, 0, 0);
                }
            }
        }

#pragma unroll
        for (int g2 = 0; g2 < 4; g2++)
#pragma unroll
            for (int r = 0; r < 4; r++) {
                float o = acc[g2][r] / lst[r];
                O[obase + (size_t)(q0 + w * 16 + quad * 4 + r) * DM + g2 * 16 + mi] = f2b(o);
            }
    }
}

// ---------------------------------------------------------------------------
// x = LN(x + delta); writes fp32 master + bf16 shadow. One wave per row.
// ---------------------------------------------------------------------------
__global__ __launch_bounds__(256) void add_ln_kernel(
    const float* __restrict__ X, const float* __restrict__ Dl,
    const float* __restrict__ G, const float* __restrict__ Bb,
    float* __restrict__ Xout, u16* __restrict__ Bout)
{
    int tid = threadIdx.x, lane = tid & 63, w = tid >> 6;
    int row = blockIdx.x * 4 + w;
    size_t off = (size_t)row * DM;

    float v[8];
    float s = 0.f;
#pragma unroll
    for (int j = 0; j < 8; j++) {
        int c = j * 64 + lane;
        v[j] = X[off + c] + Dl[off + c];
        s += v[j];
    }
#pragma unroll
    for (int d = 1; d < 64; d <<= 1) s += __shfl_xor(s, d);
    float mean = s * (1.f / 512.f);
    float vs = 0.f;
#pragma unroll
    for (int j = 0; j < 8; j++) { float t = v[j] - mean; vs += t * t; }
#pragma unroll
    for (int d = 1; d < 64; d <<= 1) vs += __shfl_xor(vs, d);
    float rstd = rsqrtf(vs * (1.f / 512.f) + 1e-5f);
#pragma unroll
    for (int j = 0; j < 8; j++) {
        int c = j * 64 + lane;
        float o = (v[j] - mean) * rstd * G[c] + Bb[c];
        Xout[off + c] = o;
        Bout[off + c] = f2b(o);
    }
}

// ---------------------------------------------------------------------------
extern "C" void kernel_launch(void* const* d_in, const int* in_sizes, int n_in,
                              void* d_out, int out_size, void* d_ws, size_t ws_size,
                              hipStream_t stream)
{
    const int*   src  = (const int*)d_in[0];
    const float* emb  = (const float*)d_in[1];
    const float* ln_g = (const float*)d_in[2];
    const float* ln_b = (const float*)d_in[3];
    const float* wq = (const float*)d_in[4];
    const float* bq = (const float*)d_in[5];
    const float* wk = (const float*)d_in[6];
    const float* bk = (const float*)d_in[7];
    const float* wv = (const float*)d_in[8];
    const float* bv = (const float*)d_in[9];
    const float* wo = (const float*)d_in[10];
    const float* bo = (const float*)d_in[11];
    const float* w1 = (const float*)d_in[12];
    const float* b1 = (const float*)d_in[13];
    const float* w2 = (const float*)d_in[14];
    const float* b2 = (const float*)d_in[15];

    char* ws = (char*)d_ws;
    float* xf  = (float*)(ws);
    u16*   xb  = (u16*)(ws + (16u << 20));
    u16*   qkv = (u16*)(ws + (24u << 20));
    u16*   ab  = (u16*)(ws + (48u << 20));
    u16*   h1  = (u16*)(ws + (24u << 20));   // aliases qkv+ab
    float* dlt = (float*)(ws + (56u << 20));
    u16*   wbf = (u16*)(ws + (72u << 20));

    u16* qkvt = wbf;                              // [L][1536][512]
    u16* wot  = wbf + 6u * 1536 * 512;            // [L][512][512]
    u16* w1t  = wot + 6u * 512 * 512;             // [L][2048][512]
    u16* w2t  = w1t + 6u * 512 * 2048;            // [L][512][2048]

    const int ROWS = 4 * S_LEN;   // 8192

    transp_kernel<<<dim3(8, 8, 6),  256, 0, stream>>>(wq, qkvt, 512, 512, 1536u * 512, 0);
    transp_kernel<<<dim3(8, 8, 6),  256, 0, stream>>>(wk, qkvt, 512, 512, 1536u * 512, 512);
    transp_kernel<<<dim3(8, 8, 6),  256, 0, stream>>>(wv, qkvt, 512, 512, 1536u * 512, 1024);
    transp_kernel<<<dim3(8, 8, 6),  256, 0, stream>>>(wo, wot, 512, 512, 512u * 512, 0);
    transp_kernel<<<dim3(32, 8, 6), 256, 0, stream>>>(w1, w1t, 512, 2048, 2048u * 512, 0);
    transp_kernel<<<dim3(8, 32, 6), 256, 0, stream>>>(w2, w2t, 2048, 512, 512u * 2048, 0);

    embed_kernel<<<ROWS / 4, 256, 0, stream>>>(src, emb, xf, xb);

    dim3 gqkv(1536 / 128, ROWS / 128);
    dim3 g512(512 / 64, ROWS / 128);     // NT=64 tiles
    dim3 g2048(2048 / 128, ROWS / 128);
    dim3 gattn(16, 4 * NHEAD);

    for (int l = 0; l < 6; l++) {
        const u16* Wqkv = qkvt + (size_t)l * 1536 * 512;
        const u16* Wo   = wot + (size_t)l * 512 * 512;
        const u16* W1   = w1t + (size_t)l * 2048 * 512;
        const u16* W2   = w2t + (size_t)l * 512 * 2048;
        const float* Bq = bq + l * DM;
        const float* Bk = bk + l * DM;
        const float* Bv = bv + l * DM;
        const float* Bo = bo + l * DM;
        const float* B1 = b1 + l * FF;
        const float* B2 = b2 + l * DM;

        gemm_kernel<0, false, 128><<<gqkv, 256, 0, stream>>>(
            xb, Wqkv, Bq, Bk, Bv, Bv, qkv, QKV_STRIDE, 512);

        attn_kernel<<<gattn, 256, 0, stream>>>(qkv, ab);

        gemm_kernel<0, true, 64><<<g512, 256, 0, stream>>>(
            ab, Wo, Bo, Bo, Bo, Bo, dlt, 512, 512);
        add_ln_kernel<<<ROWS / 4, 256, 0, stream>>>(xf, dlt, ln_g, ln_b, xf, xb);

        gemm_kernel<1, false, 128><<<g2048, 256, 0, stream>>>(
            xb, W1, B1, B1 + 512, B1 + 1024, B1 + 1536, h1, FF, 512);
        gemm_kernel<1, true, 64><<<g512, 256, 0, stream>>>(
            h1, W2, B2, B2, B2, B2, dlt, 512, 2048);
        add_ln_kernel<<<ROWS / 4, 256, 0, stream>>>(xf, dlt, ln_g, ln_b,
                                                    (l == 5) ? (float*)d_out : xf, xb);
    }
}